// Round 6
// baseline (653.170 us; speedup 1.0000x reference)
//
#include <hip/hip_runtime.h>

#define T_STEPS 512
#define BATCH   64
#define HID     64
#define G3      192      // 3*HID
#define DIN     2048
#define B_BLK   32
#define NBLK    2        // BATCH / B_BLK
#define LOG2E   1.44269504088896340736f

typedef float  f32x4  __attribute__((ext_vector_type(4)));
typedef short  short8 __attribute__((ext_vector_type(8)));

__device__ __forceinline__ unsigned short f2bf(float f) {
    unsigned int u = __builtin_bit_cast(unsigned int, f);
    unsigned int r = u + 0x7fffu + ((u >> 16) & 1u);   // RNE
    return (unsigned short)(r >> 16);
}
// HW packed f32->bf16 (RNE), 1 instruction
__device__ __forceinline__ unsigned int cvtpk(float a, float b) {
    unsigned int r;
    asm("v_cvt_pk_bf16_f32 %0, %1, %2" : "=v"(r) : "v"(a), "v"(b));
    return r;
}
// v_exp_f32 IS 2^x on gfx9; negate folds as a free input modifier
__device__ __forceinline__ float exp2neg(float x) {   // 2^(-x)
    float r; asm("v_exp_f32 %0, -%1" : "=v"(r) : "v"(x)); return r;
}
__device__ __forceinline__ float exp2pos(float x) {   // 2^(x)
    float r; asm("v_exp_f32 %0, %1" : "=v"(r) : "v"(x)); return r;
}
// barrier WITHOUT vmcnt drain: orders LDS only; global prefetch stays in flight
__device__ __forceinline__ void wg_barrier() {
    asm volatile("s_waitcnt lgkmcnt(0)" ::: "memory");
    __builtin_amdgcn_s_barrier();
    asm volatile("" ::: "memory");
}

// Fused GRU gate unit, exp2 domain. Inputs pre-scaled:
// grs,gzs by log2e; a2 (hh n-part incl bias), xn (rest of n-arg) by 2*log2e.
__device__ __forceinline__ float gunit(float grs, float gzs, float a2,
                                       float xn, float h) {
    float R   = 1.f + exp2neg(grs);
    float Q   = 1.f + exp2neg(gzs);
    float r   = __builtin_amdgcn_rcpf(R);
    float s   = fmaf(r, a2, xn);
    float P   = 1.f + exp2pos(s);
    float ipq = __builtin_amdgcn_rcpf(P * Q);
    float n   = fmaf(-2.f, ipq * Q, 1.f);          // tanh
    return fmaf(h - n, ipq * P, n);                // n + z*(h-n)
}

// ---------------- Kernel 1: xi = (x @ W_ih0^T + b_ih0) * gate_scale --------
// Output: f32, layout xi[t][b][g], g = gate*64 + row; r,z rows scaled by
// log2e, n rows by 2*log2e (exp2-domain gates downstream).
#define BM  128
#define BK  64
#define LDA 72
#define LDB 72

__launch_bounds__(512, 1)
__global__ void proj0_kernel(const float* __restrict__ x,
                             const float* __restrict__ Wih0,
                             const float* __restrict__ bih0,
                             float* __restrict__ xi)
{
    __shared__ unsigned short Asm[BM * LDA];
    __shared__ unsigned short Bsm[G3 * LDB];

    const int tid  = threadIdx.x;
    const int wave = tid >> 6;
    const int lane = tid & 63;
    const int wm   = wave >> 2;
    const int wn   = wave & 3;
    const int m0   = blockIdx.x * BM;
    const int l16  = lane & 15;
    const int lk   = lane >> 4;
    const int rA   = tid >> 4;       // 0..31
    const int c4   = tid & 15;

    const float* xb = x    + (size_t)(m0 + rA) * DIN + c4 * 4;
    const float* wb = Wih0 + (size_t)rA        * DIN + c4 * 4;
    unsigned short* ap = Asm + rA * LDA + c4 * 4;
    unsigned short* bp = Bsm + rA * LDB + c4 * 4;

    f32x4 acc[4][3];
#pragma unroll
    for (int mi = 0; mi < 4; ++mi)
#pragma unroll
        for (int ni = 0; ni < 3; ++ni)
            acc[mi][ni] = (f32x4){0.f, 0.f, 0.f, 0.f};

    float4 stA[4], stB[6];
#pragma unroll
    for (int it = 0; it < 4; ++it) stA[it] = *(const float4*)(xb + it * 32 * DIN);
#pragma unroll
    for (int it = 0; it < 6; ++it) stB[it] = *(const float4*)(wb + it * 32 * DIN);

    for (int kt = 0; kt < DIN / BK; ++kt) {
#pragma unroll
        for (int it = 0; it < 4; ++it) {
            uint2 pk;
            pk.x = cvtpk(stA[it].x, stA[it].y);
            pk.y = cvtpk(stA[it].z, stA[it].w);
            *(uint2*)(ap + it * 32 * LDA) = pk;
        }
#pragma unroll
        for (int it = 0; it < 6; ++it) {
            uint2 pk;
            pk.x = cvtpk(stB[it].x, stB[it].y);
            pk.y = cvtpk(stB[it].z, stB[it].w);
            *(uint2*)(bp + it * 32 * LDB) = pk;
        }
        if (kt + 1 < DIN / BK) {
            const int kk = (kt + 1) * BK;
#pragma unroll
            for (int it = 0; it < 4; ++it) stA[it] = *(const float4*)(xb + kk + it * 32 * DIN);
#pragma unroll
            for (int it = 0; it < 6; ++it) stB[it] = *(const float4*)(wb + kk + it * 32 * DIN);
        }
        wg_barrier();

#pragma unroll
        for (int ks = 0; ks < 2; ++ks) {
            const int kb = ks * 32 + lk * 8;
            short8 a[4], bfr[3];
#pragma unroll
            for (int mi = 0; mi < 4; ++mi)
                a[mi] = *(const short8*)&Asm[(wm * 64 + mi * 16 + l16) * LDA + kb];
#pragma unroll
            for (int ni = 0; ni < 3; ++ni)
                bfr[ni] = *(const short8*)&Bsm[(wn * 48 + ni * 16 + l16) * LDB + kb];
#pragma unroll
            for (int mi = 0; mi < 4; ++mi)
#pragma unroll
                for (int ni = 0; ni < 3; ++ni)
                    acc[mi][ni] = __builtin_amdgcn_mfma_f32_16x16x32_bf16(
                        a[mi], bfr[ni], acc[mi][ni], 0, 0, 0);
        }
        wg_barrier();
    }

#pragma unroll
    for (int ni = 0; ni < 3; ++ni) {
        int g = wn * 48 + ni * 16 + l16;      // = gate*64 + row
        float sc = (g < 128) ? LOG2E : 2.f * LOG2E;
        float bias = bih0[g];
#pragma unroll
        for (int mi = 0; mi < 4; ++mi) {
#pragma unroll
            for (int r = 0; r < 4; ++r) {
                int m  = m0 + wm * 64 + mi * 16 + lk * 4 + r;
                int t  = m & 511;
                int bb = m >> 9;
                xi[(size_t)(t * BATCH + bb) * G3 + g] = (acc[mi][ni][r] + bias) * sc;
            }
        }
    }
}

// ---------------- Kernel 2: MFMA-batched fused 2-layer GRU + FC ------------
// 2 blocks x 32 batch x 16 waves (1024 thr) -> 4 waves/SIMD (2 L0 + 2 L1)
// so dependency stalls of one wave are filled by the other three.
// Two independent batch-16 pipelines per block share the per-step barrier.
// role 0 (w<8):  h0(t) = gates(xi(t), Whh0@h0(t-1));  6 MFMA + 4 gate units
// role 1 (w>=8): h1(t-1) via Wih1@h0(t-1) + Whh1@h1(t-2); 12 MFMA + 4 units
__launch_bounds__(1024)
__global__ void gru_fused_kernel(const float* __restrict__ xi,
                                 const float* __restrict__ Whh0,
                                 const float* __restrict__ bhh0,
                                 const float* __restrict__ Wih1,
                                 const float* __restrict__ bih1,
                                 const float* __restrict__ Whh1,
                                 const float* __restrict__ bhh1,
                                 const float* __restrict__ fcw,
                                 const float* __restrict__ fcb,
                                 float* __restrict__ out)
{
    __shared__ __align__(16) unsigned short h0d[2][2][8][16][8];  // [beta][buf][chunk][c][8]
    __shared__ __align__(16) unsigned short h1d[2][2][8][16][8];
    __shared__ float fcbuf[B_BLK][68];

    const int tid  = threadIdx.x;
    const int w    = tid >> 6;        // wave 0..15
    const int l    = tid & 63;
    const int c    = l & 15;          // batch-in-16 / MFMA col
    const int kg   = l >> 4;          // 0..3
    const int blk  = blockIdx.x;
    const int role = w >> 3;          // 0 = L0, 1 = L1
    const int beta = (w >> 2) & 1;    // batch-half
    const int sub  = w & 3;           // row-block
    const int jw   = sub * 16;

    // ---- stationary weight fragments + bias C-inits (exp2-prescaled) ----
    short8 fragP[6], fragQ[6];        // role0: Whh0 / dup ; role1: Wih1 / Whh1
    f32x4  bP[3];                     // role0: bhh0 ; role1: {bih1+bhh1 (r,z), bih1 (n)}
    f32x4  bQ;                        // role1 only: bhh1 n-rows (C-init of g2)
    {
        const float* WP = role ? Wih1 : Whh0;
        const float* WQ = role ? Whh1 : Whh0;
#pragma unroll
        for (int g = 0; g < 3; ++g) {
            const float sc = (g == 2) ? 2.f * LOG2E : LOG2E;
#pragma unroll
            for (int ks = 0; ks < 2; ++ks) {
                const size_t roff = (size_t)(g * 64 + jw + c) * HID + ks * 32 + kg * 8;
                short8 s, q;
#pragma unroll
                for (int j = 0; j < 8; ++j) s[j] = (short)f2bf(WP[roff + j] * sc);
#pragma unroll
                for (int j = 0; j < 8; ++j) q[j] = (short)f2bf(WQ[roff + j] * sc);
                fragP[g * 2 + ks] = s;
                fragQ[g * 2 + ks] = q;
            }
            float4 v1 = *(const float4*)&(role ? bih1 : bhh0)[g * 64 + jw + kg * 4];
            float4 v2 = *(const float4*)&(role ? bhh1 : bhh0)[g * 64 + jw + kg * 4];
            if (role && g < 2) {            // r,z: both biases sum linearly
                bP[g] = (f32x4){(v1.x + v2.x) * sc, (v1.y + v2.y) * sc,
                                (v1.z + v2.z) * sc, (v1.w + v2.w) * sc};
            } else {
                bP[g] = (f32x4){v1.x * sc, v1.y * sc, v1.z * sc, v1.w * sc};
            }
            if (g == 2)
                bQ = (f32x4){v2.x * sc, v2.y * sc, v2.z * sc, v2.w * sc};
        }
    }

    float hst[4] = {0.f, 0.f, 0.f, 0.f};   // role0: h0 slice; role1: h1 slice

    // zero h buffers (2048 dwords each)
    for (int i = tid; i < 2048; i += 1024) {
        ((unsigned int*)h0d)[i] = 0;
        ((unsigned int*)h1d)[i] = 0;
    }
    __syncthreads();

    const int chunk = 2 * sub + (kg >> 1);
    const int coff  = (kg & 1) * 4;

    if (role == 0) {
        // ---- L0 loop: xi global->reg depth-2 prefetch, 6 MFMA, 4 units ----
        const float* xp = xi + (size_t)(blk * B_BLK + beta * 16 + c) * G3 + jw + kg * 4;
        float4 pA[3], pB[3];
        pA[0] = *(const float4*)(xp);
        pA[1] = *(const float4*)(xp + 64);
        pA[2] = *(const float4*)(xp + 128);
        {
            const float* p1 = xp + (size_t)BATCH * G3;
            pB[0] = *(const float4*)(p1);
            pB[1] = *(const float4*)(p1 + 64);
            pB[2] = *(const float4*)(p1 + 128);
        }

        auto stepL0 = [&](int t, float4 (&cur)[3]) {
            if (t < T_STEPS) {
                const int pb = (t + 1) & 1;
                short8 x0 = *(const short8*)&h0d[beta][pb][kg][c][0];
                short8 x1 = *(const short8*)&h0d[beta][pb][4 + kg][c][0];
                f32x4 a0 = bP[0], a1 = bP[1], a2 = bP[2];
                a0 = __builtin_amdgcn_mfma_f32_16x16x32_bf16(fragP[0], x0, a0, 0, 0, 0);
                a0 = __builtin_amdgcn_mfma_f32_16x16x32_bf16(fragP[1], x1, a0, 0, 0, 0);
                a1 = __builtin_amdgcn_mfma_f32_16x16x32_bf16(fragP[2], x0, a1, 0, 0, 0);
                a1 = __builtin_amdgcn_mfma_f32_16x16x32_bf16(fragP[3], x1, a1, 0, 0, 0);
                a2 = __builtin_amdgcn_mfma_f32_16x16x32_bf16(fragP[4], x0, a2, 0, 0, 0);
                a2 = __builtin_amdgcn_mfma_f32_16x16x32_bf16(fragP[5], x1, a2, 0, 0, 0);

                float4 xr4 = cur[0], xz4 = cur[1], xn4 = cur[2];
                if (t + 2 < T_STEPS) {       // refill; rides across barriers
                    const float* p = xp + (size_t)(t + 2) * (BATCH * G3);
                    cur[0] = *(const float4*)(p);
                    cur[1] = *(const float4*)(p + 64);
                    cur[2] = *(const float4*)(p + 128);
                }
                hst[0] = gunit(xr4.x + a0[0], xz4.x + a1[0], a2[0], xn4.x, hst[0]);
                hst[1] = gunit(xr4.y + a0[1], xz4.y + a1[1], a2[1], xn4.y, hst[1]);
                hst[2] = gunit(xr4.z + a0[2], xz4.z + a1[2], a2[2], xn4.z, hst[2]);
                hst[3] = gunit(xr4.w + a0[3], xz4.w + a1[3], a2[3], xn4.w, hst[3]);
                uint2 hw;
                hw.x = cvtpk(hst[0], hst[1]);
                hw.y = cvtpk(hst[2], hst[3]);
                *(uint2*)&h0d[beta][t & 1][chunk][c][coff] = hw;
            }
            wg_barrier();
        };

        for (int tt = 0; tt < T_STEPS + 2; tt += 2) {
            stepL0(tt, pA);
            stepL0(tt + 1, pB);
        }
    } else {
        // ---- L1 loop: 12 MFMA on h0(t-1), h1(t-2); 4 gate units ----
        auto stepL1 = [&](int t) {
            if (t >= 1 && t <= T_STEPS) {
                const int pb = (t + 1) & 1;            // h0(t-1)
                const int p1 = t & 1;                  // h1(t-2)
                short8 x0 = *(const short8*)&h0d[beta][pb][kg][c][0];
                short8 x1 = *(const short8*)&h0d[beta][pb][4 + kg][c][0];
                short8 y0 = *(const short8*)&h1d[beta][p1][kg][c][0];
                short8 y1 = *(const short8*)&h1d[beta][p1][4 + kg][c][0];
                f32x4 i0 = bP[0], i1 = bP[1], i2 = bP[2];
                f32x4 g0 = (f32x4){0.f, 0.f, 0.f, 0.f};
                f32x4 g1 = (f32x4){0.f, 0.f, 0.f, 0.f};
                f32x4 g2 = bQ;
                i0 = __builtin_amdgcn_mfma_f32_16x16x32_bf16(fragP[0], x0, i0, 0, 0, 0);
                i0 = __builtin_amdgcn_mfma_f32_16x16x32_bf16(fragP[1], x1, i0, 0, 0, 0);
                i1 = __builtin_amdgcn_mfma_f32_16x16x32_bf16(fragP[2], x0, i1, 0, 0, 0);
                i1 = __builtin_amdgcn_mfma_f32_16x16x32_bf16(fragP[3], x1, i1, 0, 0, 0);
                i2 = __builtin_amdgcn_mfma_f32_16x16x32_bf16(fragP[4], x0, i2, 0, 0, 0);
                i2 = __builtin_amdgcn_mfma_f32_16x16x32_bf16(fragP[5], x1, i2, 0, 0, 0);
                g0 = __builtin_amdgcn_mfma_f32_16x16x32_bf16(fragQ[0], y0, g0, 0, 0, 0);
                g0 = __builtin_amdgcn_mfma_f32_16x16x32_bf16(fragQ[1], y1, g0, 0, 0, 0);
                g1 = __builtin_amdgcn_mfma_f32_16x16x32_bf16(fragQ[2], y0, g1, 0, 0, 0);
                g1 = __builtin_amdgcn_mfma_f32_16x16x32_bf16(fragQ[3], y1, g1, 0, 0, 0);
                g2 = __builtin_amdgcn_mfma_f32_16x16x32_bf16(fragQ[4], y0, g2, 0, 0, 0);
                g2 = __builtin_amdgcn_mfma_f32_16x16x32_bf16(fragQ[5], y1, g2, 0, 0, 0);
#pragma unroll
                for (int q = 0; q < 4; ++q)
                    hst[q] = gunit(i0[q] + g0[q], i1[q] + g1[q], g2[q], i2[q], hst[q]);
                uint2 hw;
                hw.x = cvtpk(hst[0], hst[1]);
                hw.y = cvtpk(hst[2], hst[3]);
                *(uint2*)&h1d[beta][(t + 1) & 1][chunk][c][coff] = hw;   // h1(t-1)
            }
            wg_barrier();
        };

        for (int tt = 0; tt < T_STEPS + 2; tt += 2) {
            stepL1(tt);
            stepL1(tt + 1);
        }
    }

    // ---- FC: out[b] = h1(511) . fc_w + fc_b ----
    if (role == 1) {
#pragma unroll
        for (int q = 0; q < 4; ++q)
            fcbuf[beta * 16 + c][jw + kg * 4 + q] = hst[q];
    }
    __syncthreads();
    if (w < 2) {
        float p = 0.f;
#pragma unroll
        for (int jj = 0; jj < 16; ++jj)
            p += fcbuf[w * 16 + c][kg * 16 + jj] * fcw[kg * 16 + jj];
        p += __shfl_xor(p, 16);
        p += __shfl_xor(p, 32);
        if (kg == 0) out[blk * B_BLK + w * 16 + c] = p + fcb[0];
    }
}

extern "C" void kernel_launch(void* const* d_in, const int* in_sizes, int n_in,
                              void* d_out, int out_size, void* d_ws, size_t ws_size,
                              hipStream_t stream)
{
    const float* x    = (const float*)d_in[0];
    const float* Wih0 = (const float*)d_in[1];
    const float* Whh0 = (const float*)d_in[2];
    const float* bih0 = (const float*)d_in[3];
    const float* bhh0 = (const float*)d_in[4];
    const float* Wih1 = (const float*)d_in[5];
    const float* Whh1 = (const float*)d_in[6];
    const float* bih1 = (const float*)d_in[7];
    const float* bhh1 = (const float*)d_in[8];
    const float* fcw  = (const float*)d_in[9];
    const float* fcb  = (const float*)d_in[10];
    float* out = (float*)d_out;
    float* xi  = (float*)d_ws;   // 512*64*192 f32 = 25.2 MB (pre-scaled)

    hipLaunchKernelGGL(proj0_kernel, dim3(32768 / BM), dim3(512), 0, stream,
                       x, Wih0, bih0, xi);
    hipLaunchKernelGGL(gru_fused_kernel, dim3(NBLK), dim3(1024), 0, stream,
                       xi, Whh0, bhh0, Wih1, bih1, Whh1, bhh1, fcw, fcb, out);
}

// Round 7
// 523.208 us; speedup vs baseline: 1.2484x; 1.2484x over previous
//
#include <hip/hip_runtime.h>

#define T_STEPS 512
#define BATCH   64
#define HID     64
#define G3      192      // 3*HID
#define DIN     2048
#define B_BLK   16
#define NBLK    4        // BATCH / B_BLK
#define LOG2E   1.44269504088896340736f
#define LDP     196      // pbuf pad (f32 per batch col)

typedef float  f32x4  __attribute__((ext_vector_type(4)));
typedef short  short8 __attribute__((ext_vector_type(8)));

__device__ __forceinline__ unsigned short f2bf(float f) {
    unsigned int u = __builtin_bit_cast(unsigned int, f);
    unsigned int r = u + 0x7fffu + ((u >> 16) & 1u);   // RNE
    return (unsigned short)(r >> 16);
}
// HW packed f32->bf16 (RNE), 1 instruction
__device__ __forceinline__ unsigned int cvtpk(float a, float b) {
    unsigned int r;
    asm("v_cvt_pk_bf16_f32 %0, %1, %2" : "=v"(r) : "v"(a), "v"(b));
    return r;
}
// v_exp_f32 IS 2^x on gfx9; negate folds as a free input modifier
__device__ __forceinline__ float exp2neg(float x) {   // 2^(-x)
    float r; asm("v_exp_f32 %0, -%1" : "=v"(r) : "v"(x)); return r;
}
__device__ __forceinline__ float exp2pos(float x) {   // 2^(x)
    float r; asm("v_exp_f32 %0, %1" : "=v"(r) : "v"(x)); return r;
}
// barrier WITHOUT vmcnt drain: orders LDS only; global prefetch stays in flight
__device__ __forceinline__ void wg_barrier() {
    asm volatile("s_waitcnt lgkmcnt(0)" ::: "memory");
    __builtin_amdgcn_s_barrier();
    asm volatile("" ::: "memory");
}

// Fused GRU gate unit, exp2 domain (inputs pre-scaled by log2e / 2*log2e).
__device__ __forceinline__ float gunit(float grs, float gzs, float a2,
                                       float xn, float h) {
    float R   = 1.f + exp2neg(grs);
    float Q   = 1.f + exp2neg(gzs);
    float r   = __builtin_amdgcn_rcpf(R);
    float s   = fmaf(r, a2, xn);
    float P   = 1.f + exp2pos(s);
    float ipq = __builtin_amdgcn_rcpf(P * Q);
    float n   = fmaf(-2.f, ipq * Q, 1.f);          // tanh
    return fmaf(h - n, ipq * P, n);                // n + z*(h-n)
}

// ---------------- Kernel 1: xi = (x @ W_ih0^T + b_ih0) * gate_scale --------
// Output: f32, layout xi[t][b][g], g = gate*64 + row; r,z rows scaled by
// log2e, n rows by 2*log2e (exp2-domain gates downstream).
#define BM  128
#define BK  64
#define LDA 72
#define LDB 72

__launch_bounds__(512, 1)
__global__ void proj0_kernel(const float* __restrict__ x,
                             const float* __restrict__ Wih0,
                             const float* __restrict__ bih0,
                             float* __restrict__ xi)
{
    __shared__ unsigned short Asm[BM * LDA];
    __shared__ unsigned short Bsm[G3 * LDB];

    const int tid  = threadIdx.x;
    const int wave = tid >> 6;
    const int lane = tid & 63;
    const int wm   = wave >> 2;
    const int wn   = wave & 3;
    const int m0   = blockIdx.x * BM;
    const int l16  = lane & 15;
    const int lk   = lane >> 4;
    const int rA   = tid >> 4;       // 0..31
    const int c4   = tid & 15;

    const float* xb = x    + (size_t)(m0 + rA) * DIN + c4 * 4;
    const float* wb = Wih0 + (size_t)rA        * DIN + c4 * 4;
    unsigned short* ap = Asm + rA * LDA + c4 * 4;
    unsigned short* bp = Bsm + rA * LDB + c4 * 4;

    f32x4 acc[4][3];
#pragma unroll
    for (int mi = 0; mi < 4; ++mi)
#pragma unroll
        for (int ni = 0; ni < 3; ++ni)
            acc[mi][ni] = (f32x4){0.f, 0.f, 0.f, 0.f};

    float4 stA[4], stB[6];
#pragma unroll
    for (int it = 0; it < 4; ++it) stA[it] = *(const float4*)(xb + it * 32 * DIN);
#pragma unroll
    for (int it = 0; it < 6; ++it) stB[it] = *(const float4*)(wb + it * 32 * DIN);

    for (int kt = 0; kt < DIN / BK; ++kt) {
#pragma unroll
        for (int it = 0; it < 4; ++it) {
            uint2 pk;
            pk.x = cvtpk(stA[it].x, stA[it].y);
            pk.y = cvtpk(stA[it].z, stA[it].w);
            *(uint2*)(ap + it * 32 * LDA) = pk;
        }
#pragma unroll
        for (int it = 0; it < 6; ++it) {
            uint2 pk;
            pk.x = cvtpk(stB[it].x, stB[it].y);
            pk.y = cvtpk(stB[it].z, stB[it].w);
            *(uint2*)(bp + it * 32 * LDB) = pk;
        }
        if (kt + 1 < DIN / BK) {
            const int kk = (kt + 1) * BK;
#pragma unroll
            for (int it = 0; it < 4; ++it) stA[it] = *(const float4*)(xb + kk + it * 32 * DIN);
#pragma unroll
            for (int it = 0; it < 6; ++it) stB[it] = *(const float4*)(wb + kk + it * 32 * DIN);
        }
        wg_barrier();

#pragma unroll
        for (int ks = 0; ks < 2; ++ks) {
            const int kb = ks * 32 + lk * 8;
            short8 a[4], bfr[3];
#pragma unroll
            for (int mi = 0; mi < 4; ++mi)
                a[mi] = *(const short8*)&Asm[(wm * 64 + mi * 16 + l16) * LDA + kb];
#pragma unroll
            for (int ni = 0; ni < 3; ++ni)
                bfr[ni] = *(const short8*)&Bsm[(wn * 48 + ni * 16 + l16) * LDB + kb];
#pragma unroll
            for (int mi = 0; mi < 4; ++mi)
#pragma unroll
                for (int ni = 0; ni < 3; ++ni)
                    acc[mi][ni] = __builtin_amdgcn_mfma_f32_16x16x32_bf16(
                        a[mi], bfr[ni], acc[mi][ni], 0, 0, 0);
        }
        wg_barrier();
    }

#pragma unroll
    for (int ni = 0; ni < 3; ++ni) {
        int g = wn * 48 + ni * 16 + l16;      // = gate*64 + row
        float sc = (g < 128) ? LOG2E : 2.f * LOG2E;
        float bias = bih0[g];
#pragma unroll
        for (int mi = 0; mi < 4; ++mi) {
#pragma unroll
            for (int r = 0; r < 4; ++r) {
                int m  = m0 + wm * 64 + mi * 16 + lk * 4 + r;
                int t  = m & 511;
                int bb = m >> 9;
                xi[(size_t)(t * BATCH + bb) * G3 + g] = (acc[mi][ni][r] + bias) * sc;
            }
        }
    }
}

// ---------------- Kernel 2: MFMA-batched fused 2-layer GRU + FC ------------
// 4 blocks x 16 batch x 8 waves (2 waves/SIMD). ONE lgkm-only barrier/step.
// Role-balanced pipeline:
//  waves 0-3 (L0) @step t:  h0(t) = gates(xi(t), Whh0@h0(t-1))   [6 MFMA]
//                           AND p(t-1) = Wih1@h0(t-1) + biases   [6 MFMA,
//                           reuses the already-loaded h0(t-1) B-frags] -> pbuf
//  waves 4-7 (L1) @step t:  h1(t-2) = gates(p(t-2), Whh1@h1(t-3)) [6 MFMA]
// L1 lags 2 steps; FC from registers at the end.
__launch_bounds__(512, 1)
__global__ void gru_fused_kernel(const float* __restrict__ xi,
                                 const float* __restrict__ Whh0,
                                 const float* __restrict__ bhh0,
                                 const float* __restrict__ Wih1,
                                 const float* __restrict__ bih1,
                                 const float* __restrict__ Whh1,
                                 const float* __restrict__ bhh1,
                                 const float* __restrict__ fcw,
                                 const float* __restrict__ fcb,
                                 float* __restrict__ out)
{
    __shared__ __align__(16) unsigned short h0d[2][8][B_BLK][8];  // 4 KB
    __shared__ __align__(16) unsigned short h1d[2][8][B_BLK][8];  // 4 KB
    __shared__ __align__(16) float pbuf[2][B_BLK][LDP];           // 24.5 KB
    __shared__ float fcbuf[B_BLK][68];

    const int tid  = threadIdx.x;
    const int w    = tid >> 6;        // wave 0..7
    const int l    = tid & 63;
    const int c    = l & 15;          // batch-in-block / MFMA col
    const int kg   = l >> 4;          // 0..3
    const int blk  = blockIdx.x;
    const int role = w >> 2;          // 0 = L0, 1 = L1
    const int sub  = w & 3;
    const int jw   = sub * 16;

    // ---- stationary weight fragments + bias C-inits (exp2-prescaled) ----
    // role 0: fragP = Whh0 rows, fragQ = Wih1 rows
    //         bP = bhh0*sc (C-init of h0-gate accs)
    //         bQ = { (bih1+bhh1)*sc (r,z), bih1*2log2e (n) } (C-init of partial)
    // role 1: fragP = Whh1 rows; bP = { 0, 0, bhh1_n*2log2e } (C-init g-accs)
    short8 fragP[6], fragQ[6];
    f32x4  bP[3], bQ[3];
    {
        const float* WP = role ? Whh1 : Whh0;
        const float* WQ = role ? Whh1 : Wih1;      // role1: fragQ unused
#pragma unroll
        for (int g = 0; g < 3; ++g) {
            const float sc = (g == 2) ? 2.f * LOG2E : LOG2E;
#pragma unroll
            for (int ks = 0; ks < 2; ++ks) {
                const size_t roff = (size_t)(g * 64 + jw + c) * HID + ks * 32 + kg * 8;
                short8 s, q;
#pragma unroll
                for (int j = 0; j < 8; ++j) s[j] = (short)f2bf(WP[roff + j] * sc);
#pragma unroll
                for (int j = 0; j < 8; ++j) q[j] = (short)f2bf(WQ[roff + j] * sc);
                fragP[g * 2 + ks] = s;
                fragQ[g * 2 + ks] = q;
            }
            float4 vh0 = *(const float4*)&bhh0[g * 64 + jw + kg * 4];
            float4 vi1 = *(const float4*)&bih1[g * 64 + jw + kg * 4];
            float4 vh1 = *(const float4*)&bhh1[g * 64 + jw + kg * 4];
            if (role == 0) {
                bP[g] = (f32x4){vh0.x * sc, vh0.y * sc, vh0.z * sc, vh0.w * sc};
                if (g < 2)
                    bQ[g] = (f32x4){(vi1.x + vh1.x) * sc, (vi1.y + vh1.y) * sc,
                                    (vi1.z + vh1.z) * sc, (vi1.w + vh1.w) * sc};
                else
                    bQ[g] = (f32x4){vi1.x * sc, vi1.y * sc, vi1.z * sc, vi1.w * sc};
            } else {
                if (g < 2) bP[g] = (f32x4){0.f, 0.f, 0.f, 0.f};
                else       bP[g] = (f32x4){vh1.x * sc, vh1.y * sc, vh1.z * sc, vh1.w * sc};
            }
        }
    }

    float hst[4] = {0.f, 0.f, 0.f, 0.f};   // role0: h0 slice; role1: h1 slice

    // zero h rings (1024 dwords each)
    for (int i = tid; i < 1024; i += 512) {
        ((unsigned int*)h0d)[i] = 0;
        ((unsigned int*)h1d)[i] = 0;
    }
    __syncthreads();

    const int chunk = 2 * sub + (kg >> 1);
    const int coff  = (kg & 1) * 4;

    if (role == 0) {
        // ---- L0: xi depth-2 reg prefetch, 12 MFMA, 4 units, p-dump ----
        const size_t xstep = (size_t)BATCH * G3;
        const float* xp = xi + (size_t)(blk * B_BLK + c) * G3 + jw + kg * 4;
        float4 pA[3], pB[3];
        pA[0] = *(const float4*)(xp);
        pA[1] = *(const float4*)(xp + 64);
        pA[2] = *(const float4*)(xp + 128);
        pB[0] = *(const float4*)(xp + xstep);
        pB[1] = *(const float4*)(xp + xstep + 64);
        pB[2] = *(const float4*)(xp + xstep + 128);
        const float* xpr = xp + 2 * xstep;     // next refill address

        auto stepL0 = [&](int t, float4 (&cur)[3]) {
            if (t <= T_STEPS) {
                const int pb = (t + 1) & 1;
                short8 x0 = *(const short8*)&h0d[pb][kg][c][0];
                short8 x1 = *(const short8*)&h0d[pb][4 + kg][c][0];

                // partial for L1: p(t-1) = Wih1@h0(t-1) + folded biases
                if (t >= 1) {
                    f32x4 p0 = bQ[0], p1 = bQ[1], p2 = bQ[2];
                    p0 = __builtin_amdgcn_mfma_f32_16x16x32_bf16(fragQ[0], x0, p0, 0, 0, 0);
                    p0 = __builtin_amdgcn_mfma_f32_16x16x32_bf16(fragQ[1], x1, p0, 0, 0, 0);
                    p1 = __builtin_amdgcn_mfma_f32_16x16x32_bf16(fragQ[2], x0, p1, 0, 0, 0);
                    p1 = __builtin_amdgcn_mfma_f32_16x16x32_bf16(fragQ[3], x1, p1, 0, 0, 0);
                    p2 = __builtin_amdgcn_mfma_f32_16x16x32_bf16(fragQ[4], x0, p2, 0, 0, 0);
                    p2 = __builtin_amdgcn_mfma_f32_16x16x32_bf16(fragQ[5], x1, p2, 0, 0, 0);
                    float* pd = &pbuf[t & 1][c][jw + kg * 4];
                    *(f32x4*)(pd)       = p0;
                    *(f32x4*)(pd + 64)  = p1;
                    *(f32x4*)(pd + 128) = p2;
                }

                // h0(t)
                if (t < T_STEPS) {
                    f32x4 a0 = bP[0], a1 = bP[1], a2 = bP[2];
                    a0 = __builtin_amdgcn_mfma_f32_16x16x32_bf16(fragP[0], x0, a0, 0, 0, 0);
                    a0 = __builtin_amdgcn_mfma_f32_16x16x32_bf16(fragP[1], x1, a0, 0, 0, 0);
                    a1 = __builtin_amdgcn_mfma_f32_16x16x32_bf16(fragP[2], x0, a1, 0, 0, 0);
                    a1 = __builtin_amdgcn_mfma_f32_16x16x32_bf16(fragP[3], x1, a1, 0, 0, 0);
                    a2 = __builtin_amdgcn_mfma_f32_16x16x32_bf16(fragP[4], x0, a2, 0, 0, 0);
                    a2 = __builtin_amdgcn_mfma_f32_16x16x32_bf16(fragP[5], x1, a2, 0, 0, 0);

                    float4 xr4 = cur[0], xz4 = cur[1], xn4 = cur[2];
                    if (t + 2 < T_STEPS) {       // refill; rides across barriers
                        cur[0] = *(const float4*)(xpr);
                        cur[1] = *(const float4*)(xpr + 64);
                        cur[2] = *(const float4*)(xpr + 128);
                        xpr += xstep;
                    }
                    hst[0] = gunit(xr4.x + a0[0], xz4.x + a1[0], a2[0], xn4.x, hst[0]);
                    hst[1] = gunit(xr4.y + a0[1], xz4.y + a1[1], a2[1], xn4.y, hst[1]);
                    hst[2] = gunit(xr4.z + a0[2], xz4.z + a1[2], a2[2], xn4.z, hst[2]);
                    hst[3] = gunit(xr4.w + a0[3], xz4.w + a1[3], a2[3], xn4.w, hst[3]);
                    uint2 hw;
                    hw.x = cvtpk(hst[0], hst[1]);
                    hw.y = cvtpk(hst[2], hst[3]);
                    *(uint2*)&h0d[t & 1][chunk][c][coff] = hw;
                }
            }
            wg_barrier();
        };

        for (int tt = 0; tt < T_STEPS + 2; tt += 2) {
            stepL0(tt, pA);
            stepL0(tt + 1, pB);
        }
    } else {
        // ---- L1: 6 MFMA on h1(t-3), partial read, 4 units ----
        auto stepL1 = [&](int t) {
            if (t >= 2) {
                const int py = (t + 1) & 1;            // h1(t-3) slot
                short8 y0 = *(const short8*)&h1d[py][kg][c][0];
                short8 y1 = *(const short8*)&h1d[py][4 + kg][c][0];
                f32x4 g0 = bP[0], g1 = bP[1], g2 = bP[2];
                g0 = __builtin_amdgcn_mfma_f32_16x16x32_bf16(fragP[0], y0, g0, 0, 0, 0);
                g0 = __builtin_amdgcn_mfma_f32_16x16x32_bf16(fragP[1], y1, g0, 0, 0, 0);
                g1 = __builtin_amdgcn_mfma_f32_16x16x32_bf16(fragP[2], y0, g1, 0, 0, 0);
                g1 = __builtin_amdgcn_mfma_f32_16x16x32_bf16(fragP[3], y1, g1, 0, 0, 0);
                g2 = __builtin_amdgcn_mfma_f32_16x16x32_bf16(fragP[4], y0, g2, 0, 0, 0);
                g2 = __builtin_amdgcn_mfma_f32_16x16x32_bf16(fragP[5], y1, g2, 0, 0, 0);

                const float* pd = &pbuf[(t + 1) & 1][c][jw + kg * 4];  // p(t-2)
                f32x4 pr = *(const f32x4*)(pd);
                f32x4 pz = *(const f32x4*)(pd + 64);
                f32x4 pn = *(const f32x4*)(pd + 128);
#pragma unroll
                for (int q = 0; q < 4; ++q)
                    hst[q] = gunit(pr[q] + g0[q], pz[q] + g1[q], g2[q], pn[q], hst[q]);
                uint2 hw;
                hw.x = cvtpk(hst[0], hst[1]);
                hw.y = cvtpk(hst[2], hst[3]);
                *(uint2*)&h1d[t & 1][chunk][c][coff] = hw;   // h1(t-2)
            }
            wg_barrier();
        };

        for (int tt = 0; tt < T_STEPS + 2; tt += 2) {
            stepL1(tt);
            stepL1(tt + 1);
        }
    }

    // ---- FC: out[b] = h1(511) . fc_w + fc_b ----
    if (role == 1) {
#pragma unroll
        for (int q = 0; q < 4; ++q)
            fcbuf[c][jw + kg * 4 + q] = hst[q];
    }
    __syncthreads();
    if (w == 0) {
        float p = 0.f;
#pragma unroll
        for (int jj = 0; jj < 16; ++jj)
            p += fcbuf[c][kg * 16 + jj] * fcw[kg * 16 + jj];
        p += __shfl_xor(p, 16);
        p += __shfl_xor(p, 32);
        if (kg == 0) out[blk * B_BLK + c] = p + fcb[0];
    }
}

extern "C" void kernel_launch(void* const* d_in, const int* in_sizes, int n_in,
                              void* d_out, int out_size, void* d_ws, size_t ws_size,
                              hipStream_t stream)
{
    const float* x    = (const float*)d_in[0];
    const float* Wih0 = (const float*)d_in[1];
    const float* Whh0 = (const float*)d_in[2];
    const float* bih0 = (const float*)d_in[3];
    const float* bhh0 = (const float*)d_in[4];
    const float* Wih1 = (const float*)d_in[5];
    const float* Whh1 = (const float*)d_in[6];
    const float* bih1 = (const float*)d_in[7];
    const float* bhh1 = (const float*)d_in[8];
    const float* fcw  = (const float*)d_in[9];
    const float* fcb  = (const float*)d_in[10];
    float* out = (float*)d_out;
    float* xi  = (float*)d_ws;   // 512*64*192 f32 = 25.2 MB (pre-scaled)

    hipLaunchKernelGGL(proj0_kernel, dim3(32768 / BM), dim3(512), 0, stream,
                       x, Wih0, bih0, xi);
    hipLaunchKernelGGL(gru_fused_kernel, dim3(NBLK), dim3(512), 0, stream,
                       xi, Whh0, bhh0, Wih1, bih1, Whh1, bhh1, fcw, fcb, out);
}

// Round 8
// 452.864 us; speedup vs baseline: 1.4423x; 1.1553x over previous
//
#include <hip/hip_runtime.h>

#define T_STEPS 512
#define BATCH   64
#define HID     64
#define G3      192      // 3*HID
#define DIN     2048
#define B_BLK   16
#define NBLK    4        // BATCH / B_BLK
#define LOG2E   1.44269504088896340736f
#define LDP     196      // pbuf row stride (f32)

typedef float  f32x4  __attribute__((ext_vector_type(4)));
typedef short  short8 __attribute__((ext_vector_type(8)));

__device__ __forceinline__ unsigned short f2bf(float f) {
    unsigned int u = __builtin_bit_cast(unsigned int, f);
    unsigned int r = u + 0x7fffu + ((u >> 16) & 1u);   // RNE
    return (unsigned short)(r >> 16);
}
// HW packed f32->bf16 (RNE), 1 instruction
__device__ __forceinline__ unsigned int cvtpk(float a, float b) {
    unsigned int r;
    asm("v_cvt_pk_bf16_f32 %0, %1, %2" : "=v"(r) : "v"(a), "v"(b));
    return r;
}
// v_exp_f32 IS 2^x on gfx9; negate folds as a free input modifier
__device__ __forceinline__ float exp2neg(float x) {   // 2^(-x)
    float r; asm("v_exp_f32 %0, -%1" : "=v"(r) : "v"(x)); return r;
}
__device__ __forceinline__ float exp2pos(float x) {   // 2^(x)
    float r; asm("v_exp_f32 %0, %1" : "=v"(r) : "v"(x)); return r;
}
// barrier WITHOUT vmcnt drain: orders LDS only; global prefetch stays in flight
__device__ __forceinline__ void wg_barrier() {
    asm volatile("s_waitcnt lgkmcnt(0)" ::: "memory");
    __builtin_amdgcn_s_barrier();
    asm volatile("" ::: "memory");
}

// Fused GRU gate unit, exp2 domain (inputs pre-scaled by log2e / 2*log2e).
__device__ __forceinline__ float gunit(float grs, float gzs, float a2,
                                       float xn, float h) {
    float R   = 1.f + exp2neg(grs);
    float Q   = 1.f + exp2neg(gzs);
    float r   = __builtin_amdgcn_rcpf(R);
    float s   = fmaf(r, a2, xn);
    float P   = 1.f + exp2pos(s);
    float ipq = __builtin_amdgcn_rcpf(P * Q);
    float n   = fmaf(-2.f, ipq * Q, 1.f);          // tanh
    return fmaf(h - n, ipq * P, n);                // n + z*(h-n)
}

// ---------------- Kernel 1: xi = (x @ W_ih0^T + b_ih0) * gate_scale --------
// Output: f32, layout xi[t][b][g], g = gate*64 + row; r,z rows scaled by
// log2e, n rows by 2*log2e (exp2-domain gates downstream).
#define BM  128
#define BK  64
#define LDA 72
#define LDB 72

__launch_bounds__(512, 1)
__global__ void proj0_kernel(const float* __restrict__ x,
                             const float* __restrict__ Wih0,
                             const float* __restrict__ bih0,
                             float* __restrict__ xi)
{
    __shared__ unsigned short Asm[BM * LDA];
    __shared__ unsigned short Bsm[G3 * LDB];

    const int tid  = threadIdx.x;
    const int wave = tid >> 6;
    const int lane = tid & 63;
    const int wm   = wave >> 2;
    const int wn   = wave & 3;
    const int m0   = blockIdx.x * BM;
    const int l16  = lane & 15;
    const int lk   = lane >> 4;
    const int rA   = tid >> 4;       // 0..31
    const int c4   = tid & 15;

    const float* xb = x    + (size_t)(m0 + rA) * DIN + c4 * 4;
    const float* wb = Wih0 + (size_t)rA        * DIN + c4 * 4;
    unsigned short* ap = Asm + rA * LDA + c4 * 4;
    unsigned short* bp = Bsm + rA * LDB + c4 * 4;

    f32x4 acc[4][3];
#pragma unroll
    for (int mi = 0; mi < 4; ++mi)
#pragma unroll
        for (int ni = 0; ni < 3; ++ni)
            acc[mi][ni] = (f32x4){0.f, 0.f, 0.f, 0.f};

    float4 stA[4], stB[6];
#pragma unroll
    for (int it = 0; it < 4; ++it) stA[it] = *(const float4*)(xb + it * 32 * DIN);
#pragma unroll
    for (int it = 0; it < 6; ++it) stB[it] = *(const float4*)(wb + it * 32 * DIN);

    for (int kt = 0; kt < DIN / BK; ++kt) {
#pragma unroll
        for (int it = 0; it < 4; ++it) {
            uint2 pk;
            pk.x = cvtpk(stA[it].x, stA[it].y);
            pk.y = cvtpk(stA[it].z, stA[it].w);
            *(uint2*)(ap + it * 32 * LDA) = pk;
        }
#pragma unroll
        for (int it = 0; it < 6; ++it) {
            uint2 pk;
            pk.x = cvtpk(stB[it].x, stB[it].y);
            pk.y = cvtpk(stB[it].z, stB[it].w);
            *(uint2*)(bp + it * 32 * LDB) = pk;
        }
        if (kt + 1 < DIN / BK) {
            const int kk = (kt + 1) * BK;
#pragma unroll
            for (int it = 0; it < 4; ++it) stA[it] = *(const float4*)(xb + kk + it * 32 * DIN);
#pragma unroll
            for (int it = 0; it < 6; ++it) stB[it] = *(const float4*)(wb + kk + it * 32 * DIN);
        }
        wg_barrier();

#pragma unroll
        for (int ks = 0; ks < 2; ++ks) {
            const int kb = ks * 32 + lk * 8;
            short8 a[4], bfr[3];
#pragma unroll
            for (int mi = 0; mi < 4; ++mi)
                a[mi] = *(const short8*)&Asm[(wm * 64 + mi * 16 + l16) * LDA + kb];
#pragma unroll
            for (int ni = 0; ni < 3; ++ni)
                bfr[ni] = *(const short8*)&Bsm[(wn * 48 + ni * 16 + l16) * LDB + kb];
#pragma unroll
            for (int mi = 0; mi < 4; ++mi)
#pragma unroll
                for (int ni = 0; ni < 3; ++ni)
                    acc[mi][ni] = __builtin_amdgcn_mfma_f32_16x16x32_bf16(
                        a[mi], bfr[ni], acc[mi][ni], 0, 0, 0);
        }
        wg_barrier();
    }

#pragma unroll
    for (int ni = 0; ni < 3; ++ni) {
        int g = wn * 48 + ni * 16 + l16;      // = gate*64 + row
        float sc = (g < 128) ? LOG2E : 2.f * LOG2E;
        float bias = bih0[g];
#pragma unroll
        for (int mi = 0; mi < 4; ++mi) {
#pragma unroll
            for (int r = 0; r < 4; ++r) {
                int m  = m0 + wm * 64 + mi * 16 + lk * 4 + r;
                int t  = m & 511;
                int bb = m >> 9;
                xi[(size_t)(t * BATCH + bb) * G3 + g] = (acc[mi][ni][r] + bias) * sc;
            }
        }
    }
}

// ---------------- Kernel 2: MFMA-batched fused 2-layer GRU + FC ------------
// 4 blocks x 16 batch x 12 waves (3 waves/SIMD: one of each role per SIMD).
// ONE lgkm-only barrier/step. Roles (each light, single-purpose):
//  L0 (w0-3)  @t: h0(t)   = gates(xi(t), Whh0@h0(t-1))         [6 MFMA+4 gu]
//  P  (w4-7)  @t: p(t-1)  = Wih1@h0(t-1) + folded biases       [6 MFMA] -> pbuf
//  L1 (w8-11) @t: h1(t-2) = gates(p(t-2), Whh1@h1(t-3))        [6 MFMA+4 gu]
// L0 waves get s_setprio(1): they carry the serial h0 chain; P/L1 have slack.
__launch_bounds__(768, 1)
__global__ void gru_fused_kernel(const float* __restrict__ xi,
                                 const float* __restrict__ Whh0,
                                 const float* __restrict__ bhh0,
                                 const float* __restrict__ Wih1,
                                 const float* __restrict__ bih1,
                                 const float* __restrict__ Whh1,
                                 const float* __restrict__ bhh1,
                                 const float* __restrict__ fcw,
                                 const float* __restrict__ fcb,
                                 float* __restrict__ out)
{
    __shared__ __align__(16) unsigned short h0d[2][8][B_BLK][8];  // 4 KB
    __shared__ __align__(16) unsigned short h1d[2][8][B_BLK][8];  // 4 KB
    __shared__ __align__(16) float pbuf[2][B_BLK][LDP];           // 24.5 KB
    __shared__ float fcbuf[B_BLK][68];

    const int tid  = threadIdx.x;
    const int w    = tid >> 6;        // wave 0..11
    const int l    = tid & 63;
    const int c    = l & 15;          // batch-in-block / MFMA col
    const int kg   = l >> 4;          // 0..3
    const int blk  = blockIdx.x;
    const int role = w >> 2;          // 0 = L0, 1 = P, 2 = L1
    const int sub  = w & 3;
    const int jw   = sub * 16;

    // ---- stationary weight fragments + bias C-inits (exp2-prescaled) ----
    short8 frag[6];
    f32x4  bC[3];
    {
        const float* Wsel = (role == 0) ? Whh0 : (role == 1) ? Wih1 : Whh1;
#pragma unroll
        for (int g = 0; g < 3; ++g) {
            const float sc = (g == 2) ? 2.f * LOG2E : LOG2E;
#pragma unroll
            for (int ks = 0; ks < 2; ++ks) {
                const size_t roff = (size_t)(g * 64 + jw + c) * HID + ks * 32 + kg * 8;
                short8 s;
#pragma unroll
                for (int j = 0; j < 8; ++j) s[j] = (short)f2bf(Wsel[roff + j] * sc);
                frag[g * 2 + ks] = s;
            }
            float4 vh0 = *(const float4*)&bhh0[g * 64 + jw + kg * 4];
            float4 vi1 = *(const float4*)&bih1[g * 64 + jw + kg * 4];
            float4 vh1 = *(const float4*)&bhh1[g * 64 + jw + kg * 4];
            if (role == 0) {
                bC[g] = (f32x4){vh0.x * sc, vh0.y * sc, vh0.z * sc, vh0.w * sc};
            } else if (role == 1) {
                if (g < 2)
                    bC[g] = (f32x4){(vi1.x + vh1.x) * sc, (vi1.y + vh1.y) * sc,
                                    (vi1.z + vh1.z) * sc, (vi1.w + vh1.w) * sc};
                else
                    bC[g] = (f32x4){vi1.x * sc, vi1.y * sc, vi1.z * sc, vi1.w * sc};
            } else {
                if (g < 2) bC[g] = (f32x4){0.f, 0.f, 0.f, 0.f};
                else       bC[g] = (f32x4){vh1.x * sc, vh1.y * sc, vh1.z * sc, vh1.w * sc};
            }
        }
    }

    float hst[4] = {0.f, 0.f, 0.f, 0.f};   // L0: h0 slice; L1: h1 slice

    // zero h rings (1024 dwords each)
    for (int i = tid; i < 1024; i += 768) {
        ((unsigned int*)h0d)[i] = 0;
        ((unsigned int*)h1d)[i] = 0;
    }
    __syncthreads();

    const int chunk = 2 * sub + (kg >> 1);
    const int coff  = (kg & 1) * 4;

    if (role == 0) {
        __builtin_amdgcn_s_setprio(1);     // L0 carries the serial h0 chain
        // ---- L0: xi depth-2 reg prefetch, 6 MFMA, 4 gate units ----
        const size_t xstep = (size_t)BATCH * G3;
        const float* xp = xi + (size_t)(blk * B_BLK + c) * G3 + jw + kg * 4;
        float4 pA[3], pB[3];
        pA[0] = *(const float4*)(xp);
        pA[1] = *(const float4*)(xp + 64);
        pA[2] = *(const float4*)(xp + 128);
        pB[0] = *(const float4*)(xp + xstep);
        pB[1] = *(const float4*)(xp + xstep + 64);
        pB[2] = *(const float4*)(xp + xstep + 128);
        const float* xpr = xp + 2 * xstep;

        auto stepL0 = [&](int t, float4 (&cur)[3]) {
            if (t < T_STEPS) {
                const int pb = (t + 1) & 1;
                short8 x0 = *(const short8*)&h0d[pb][kg][c][0];
                short8 x1 = *(const short8*)&h0d[pb][4 + kg][c][0];
                f32x4 a0 = bC[0], a1 = bC[1], a2 = bC[2];
                a0 = __builtin_amdgcn_mfma_f32_16x16x32_bf16(frag[0], x0, a0, 0, 0, 0);
                a0 = __builtin_amdgcn_mfma_f32_16x16x32_bf16(frag[1], x1, a0, 0, 0, 0);
                a1 = __builtin_amdgcn_mfma_f32_16x16x32_bf16(frag[2], x0, a1, 0, 0, 0);
                a1 = __builtin_amdgcn_mfma_f32_16x16x32_bf16(frag[3], x1, a1, 0, 0, 0);
                a2 = __builtin_amdgcn_mfma_f32_16x16x32_bf16(frag[4], x0, a2, 0, 0, 0);
                a2 = __builtin_amdgcn_mfma_f32_16x16x32_bf16(frag[5], x1, a2, 0, 0, 0);

                float4 xr4 = cur[0], xz4 = cur[1], xn4 = cur[2];
                if (t + 2 < T_STEPS) {       // refill; rides across barriers
                    cur[0] = *(const float4*)(xpr);
                    cur[1] = *(const float4*)(xpr + 64);
                    cur[2] = *(const float4*)(xpr + 128);
                    xpr += xstep;
                }
                hst[0] = gunit(xr4.x + a0[0], xz4.x + a1[0], a2[0], xn4.x, hst[0]);
                hst[1] = gunit(xr4.y + a0[1], xz4.y + a1[1], a2[1], xn4.y, hst[1]);
                hst[2] = gunit(xr4.z + a0[2], xz4.z + a1[2], a2[2], xn4.z, hst[2]);
                hst[3] = gunit(xr4.w + a0[3], xz4.w + a1[3], a2[3], xn4.w, hst[3]);
                uint2 hw;
                hw.x = cvtpk(hst[0], hst[1]);
                hw.y = cvtpk(hst[2], hst[3]);
                *(uint2*)&h0d[t & 1][chunk][c][coff] = hw;
            }
            wg_barrier();
        };

        for (int tt = 0; tt < T_STEPS + 2; tt += 2) {
            stepL0(tt, pA);
            stepL0(tt + 1, pB);
        }
    } else if (role == 1) {
        // ---- P: p(t-1) = Wih1@h0(t-1) + biases, 6 MFMA, pure matrix ----
        for (int t = 0; t < T_STEPS + 2; ++t) {
            if (t >= 1 && t <= T_STEPS) {
                const int pb = (t + 1) & 1;            // h0(t-1)
                short8 x0 = *(const short8*)&h0d[pb][kg][c][0];
                short8 x1 = *(const short8*)&h0d[pb][4 + kg][c][0];
                f32x4 p0 = bC[0], p1 = bC[1], p2 = bC[2];
                p0 = __builtin_amdgcn_mfma_f32_16x16x32_bf16(frag[0], x0, p0, 0, 0, 0);
                p0 = __builtin_amdgcn_mfma_f32_16x16x32_bf16(frag[1], x1, p0, 0, 0, 0);
                p1 = __builtin_amdgcn_mfma_f32_16x16x32_bf16(frag[2], x0, p1, 0, 0, 0);
                p1 = __builtin_amdgcn_mfma_f32_16x16x32_bf16(frag[3], x1, p1, 0, 0, 0);
                p2 = __builtin_amdgcn_mfma_f32_16x16x32_bf16(frag[4], x0, p2, 0, 0, 0);
                p2 = __builtin_amdgcn_mfma_f32_16x16x32_bf16(frag[5], x1, p2, 0, 0, 0);
                float* pd = &pbuf[(t + 1) & 1][c][jw + kg * 4];   // p(t-1) slot
                *(f32x4*)(pd)       = p0;
                *(f32x4*)(pd + 64)  = p1;
                *(f32x4*)(pd + 128) = p2;
            }
            wg_barrier();
        }
    } else {
        // ---- L1: h1(t-2) = gates(p(t-2), Whh1@h1(t-3)), 6 MFMA + 4 gu ----
        for (int t = 0; t < T_STEPS + 2; ++t) {
            if (t >= 2) {
                const int py = (t + 1) & 1;            // h1(t-3) slot
                short8 y0 = *(const short8*)&h1d[py][kg][c][0];
                short8 y1 = *(const short8*)&h1d[py][4 + kg][c][0];
                f32x4 g0 = bC[0], g1 = bC[1], g2 = bC[2];
                g0 = __builtin_amdgcn_mfma_f32_16x16x32_bf16(frag[0], y0, g0, 0, 0, 0);
                g0 = __builtin_amdgcn_mfma_f32_16x16x32_bf16(frag[1], y1, g0, 0, 0, 0);
                g1 = __builtin_amdgcn_mfma_f32_16x16x32_bf16(frag[2], y0, g1, 0, 0, 0);
                g1 = __builtin_amdgcn_mfma_f32_16x16x32_bf16(frag[3], y1, g1, 0, 0, 0);
                g2 = __builtin_amdgcn_mfma_f32_16x16x32_bf16(frag[4], y0, g2, 0, 0, 0);
                g2 = __builtin_amdgcn_mfma_f32_16x16x32_bf16(frag[5], y1, g2, 0, 0, 0);

                const float* pd = &pbuf[t & 1][c][jw + kg * 4];   // p(t-2)
                f32x4 pr = *(const f32x4*)(pd);
                f32x4 pz = *(const f32x4*)(pd + 64);
                f32x4 pn = *(const f32x4*)(pd + 128);
#pragma unroll
                for (int q = 0; q < 4; ++q)
                    hst[q] = gunit(pr[q] + g0[q], pz[q] + g1[q], g2[q], pn[q], hst[q]);
                uint2 hw;
                hw.x = cvtpk(hst[0], hst[1]);
                hw.y = cvtpk(hst[2], hst[3]);
                *(uint2*)&h1d[t & 1][chunk][c][coff] = hw;   // h1(t-2)
            }
            wg_barrier();
        }
    }

    // ---- FC: out[b] = h1(511) . fc_w + fc_b ----
    if (role == 2) {
#pragma unroll
        for (int q = 0; q < 4; ++q)
            fcbuf[c][jw + kg * 4 + q] = hst[q];
    }
    __syncthreads();
    if (w == 0) {
        float p = 0.f;
#pragma unroll
        for (int jj = 0; jj < 16; ++jj)
            p += fcbuf[c][kg * 16 + jj] * fcw[kg * 16 + jj];
        p += __shfl_xor(p, 16);
        p += __shfl_xor(p, 32);
        if (kg == 0) out[blk * B_BLK + c] = p + fcb[0];
    }
}

extern "C" void kernel_launch(void* const* d_in, const int* in_sizes, int n_in,
                              void* d_out, int out_size, void* d_ws, size_t ws_size,
                              hipStream_t stream)
{
    const float* x    = (const float*)d_in[0];
    const float* Wih0 = (const float*)d_in[1];
    const float* Whh0 = (const float*)d_in[2];
    const float* bih0 = (const float*)d_in[3];
    const float* bhh0 = (const float*)d_in[4];
    const float* Wih1 = (const float*)d_in[5];
    const float* Whh1 = (const float*)d_in[6];
    const float* bih1 = (const float*)d_in[7];
    const float* bhh1 = (const float*)d_in[8];
    const float* fcw  = (const float*)d_in[9];
    const float* fcb  = (const float*)d_in[10];
    float* out = (float*)d_out;
    float* xi  = (float*)d_ws;   // 512*64*192 f32 = 25.2 MB (pre-scaled)

    hipLaunchKernelGGL(proj0_kernel, dim3(32768 / BM), dim3(512), 0, stream,
                       x, Wih0, bih0, xi);
    hipLaunchKernelGGL(gru_fused_kernel, dim3(NBLK), dim3(768), 0, stream,
                       xi, Whh0, bhh0, Wih1, bih1, Whh1, bhh1, fcw, fcb, out);
}

// Round 9
// 439.984 us; speedup vs baseline: 1.4845x; 1.0293x over previous
//
#include <hip/hip_runtime.h>

#define T_STEPS 512
#define BATCH   64
#define HID     64
#define G3      192      // 3*HID
#define DIN     2048
#define B_BLK   16
#define NBLK    4        // BATCH / B_BLK
#define LOG2E   1.44269504088896340736f
#define LDP     196      // pbuf row stride (f32)
#define ROUNDS  258      // 2 GRU steps per round

typedef float  f32x4  __attribute__((ext_vector_type(4)));
typedef short  short8 __attribute__((ext_vector_type(8)));

__device__ __forceinline__ unsigned short f2bf(float f) {
    unsigned int u = __builtin_bit_cast(unsigned int, f);
    unsigned int r = u + 0x7fffu + ((u >> 16) & 1u);   // RNE
    return (unsigned short)(r >> 16);
}
__device__ __forceinline__ unsigned int cvtpk(float a, float b) {
    unsigned int r;
    asm("v_cvt_pk_bf16_f32 %0, %1, %2" : "=v"(r) : "v"(a), "v"(b));
    return r;
}
__device__ __forceinline__ float exp2neg(float x) {   // 2^(-x)
    float r; asm("v_exp_f32 %0, -%1" : "=v"(r) : "v"(x)); return r;
}
__device__ __forceinline__ float exp2pos(float x) {   // 2^(x)
    float r; asm("v_exp_f32 %0, %1" : "=v"(r) : "v"(x)); return r;
}
// barrier WITHOUT vmcnt drain: orders LDS only; global prefetch stays in flight
__device__ __forceinline__ void wg_barrier() {
    asm volatile("s_waitcnt lgkmcnt(0)" ::: "memory");
    __builtin_amdgcn_s_barrier();
    asm volatile("" ::: "memory");
}
// intra-cluster sync (4 waves): producer signals after its LDS data is
// complete; consumers spin on the 4 flags. LDS is CU-local, flags monotone.
__device__ __forceinline__ void flag_signal(volatile unsigned* f, unsigned tag) {
    asm volatile("s_waitcnt lgkmcnt(0)" ::: "memory");   // h-data committed
    *f = tag;
}
__device__ __forceinline__ void flag_wait(volatile unsigned* base, unsigned tag) {
    for (;;) {
        unsigned f0 = base[0], f1 = base[1], f2 = base[2], f3 = base[3];
        if (f0 >= tag && f1 >= tag && f2 >= tag && f3 >= tag) break;
    }
    asm volatile("" ::: "memory");                       // fence data reads
}

// Fused GRU gate unit, exp2 domain (inputs pre-scaled by log2e / 2*log2e).
__device__ __forceinline__ float gunit(float grs, float gzs, float a2,
                                       float xn, float h) {
    float R   = 1.f + exp2neg(grs);
    float Q   = 1.f + exp2neg(gzs);
    float r   = __builtin_amdgcn_rcpf(R);
    float s   = fmaf(r, a2, xn);
    float P   = 1.f + exp2pos(s);
    float ipq = __builtin_amdgcn_rcpf(P * Q);
    float n   = fmaf(-2.f, ipq * Q, 1.f);          // tanh
    return fmaf(h - n, ipq * P, n);                // n + z*(h-n)
}

// ---------------- Kernel 1: xi = (x @ W_ih0^T + b_ih0) * gate_scale --------
#define BM  128
#define BK  64
#define LDA 72
#define LDB 72

__launch_bounds__(512, 1)
__global__ void proj0_kernel(const float* __restrict__ x,
                             const float* __restrict__ Wih0,
                             const float* __restrict__ bih0,
                             float* __restrict__ xi)
{
    __shared__ unsigned short Asm[BM * LDA];
    __shared__ unsigned short Bsm[G3 * LDB];

    const int tid  = threadIdx.x;
    const int wave = tid >> 6;
    const int lane = tid & 63;
    const int wm   = wave >> 2;
    const int wn   = wave & 3;
    const int m0   = blockIdx.x * BM;
    const int l16  = lane & 15;
    const int lk   = lane >> 4;
    const int rA   = tid >> 4;       // 0..31
    const int c4   = tid & 15;

    const float* xb = x    + (size_t)(m0 + rA) * DIN + c4 * 4;
    const float* wb = Wih0 + (size_t)rA        * DIN + c4 * 4;
    unsigned short* ap = Asm + rA * LDA + c4 * 4;
    unsigned short* bp = Bsm + rA * LDB + c4 * 4;

    f32x4 acc[4][3];
#pragma unroll
    for (int mi = 0; mi < 4; ++mi)
#pragma unroll
        for (int ni = 0; ni < 3; ++ni)
            acc[mi][ni] = (f32x4){0.f, 0.f, 0.f, 0.f};

    float4 stA[4], stB[6];
#pragma unroll
    for (int it = 0; it < 4; ++it) stA[it] = *(const float4*)(xb + it * 32 * DIN);
#pragma unroll
    for (int it = 0; it < 6; ++it) stB[it] = *(const float4*)(wb + it * 32 * DIN);

    for (int kt = 0; kt < DIN / BK; ++kt) {
#pragma unroll
        for (int it = 0; it < 4; ++it) {
            uint2 pk;
            pk.x = cvtpk(stA[it].x, stA[it].y);
            pk.y = cvtpk(stA[it].z, stA[it].w);
            *(uint2*)(ap + it * 32 * LDA) = pk;
        }
#pragma unroll
        for (int it = 0; it < 6; ++it) {
            uint2 pk;
            pk.x = cvtpk(stB[it].x, stB[it].y);
            pk.y = cvtpk(stB[it].z, stB[it].w);
            *(uint2*)(bp + it * 32 * LDB) = pk;
        }
        if (kt + 1 < DIN / BK) {
            const int kk = (kt + 1) * BK;
#pragma unroll
            for (int it = 0; it < 4; ++it) stA[it] = *(const float4*)(xb + kk + it * 32 * DIN);
#pragma unroll
            for (int it = 0; it < 6; ++it) stB[it] = *(const float4*)(wb + kk + it * 32 * DIN);
        }
        wg_barrier();

#pragma unroll
        for (int ks = 0; ks < 2; ++ks) {
            const int kb = ks * 32 + lk * 8;
            short8 a[4], bfr[3];
#pragma unroll
            for (int mi = 0; mi < 4; ++mi)
                a[mi] = *(const short8*)&Asm[(wm * 64 + mi * 16 + l16) * LDA + kb];
#pragma unroll
            for (int ni = 0; ni < 3; ++ni)
                bfr[ni] = *(const short8*)&Bsm[(wn * 48 + ni * 16 + l16) * LDB + kb];
#pragma unroll
            for (int mi = 0; mi < 4; ++mi)
#pragma unroll
                for (int ni = 0; ni < 3; ++ni)
                    acc[mi][ni] = __builtin_amdgcn_mfma_f32_16x16x32_bf16(
                        a[mi], bfr[ni], acc[mi][ni], 0, 0, 0);
        }
        wg_barrier();
    }

#pragma unroll
    for (int ni = 0; ni < 3; ++ni) {
        int g = wn * 48 + ni * 16 + l16;      // = gate*64 + row
        float sc = (g < 128) ? LOG2E : 2.f * LOG2E;
        float bias = bih0[g];
#pragma unroll
        for (int mi = 0; mi < 4; ++mi) {
#pragma unroll
            for (int r = 0; r < 4; ++r) {
                int m  = m0 + wm * 64 + mi * 16 + lk * 4 + r;
                int t  = m & 511;
                int bb = m >> 9;
                xi[(size_t)(t * BATCH + bb) * G3 + g] = (acc[mi][ni][r] + bias) * sc;
            }
        }
    }
}

// ---------------- Kernel 2: MFMA-batched fused 2-layer GRU + FC ------------
// 4 blocks x 16 batch x 12 waves (3/SIMD: one of each role per SIMD).
// TWO GRU steps per WG barrier; mid-round h-exchange via 4-wave LDS flag
// spin (only the serial-chain cluster syncs; P never spins). 4-deep rings.
//  L0 (w0-3)  @round r: h0(2r), h0(2r+1)                 [2x(6 MFMA+4 gu)]
//  P  (w4-7)  @round r: p(2r-2), p(2r-1) = Wih1@h0+biases [2x 6 MFMA]
//  L1 (w8-11) @round r: h1(2r-4), h1(2r-3)               [2x(6 MFMA+4 gu)]
__launch_bounds__(768, 1)
__global__ void gru_fused_kernel(const float* __restrict__ xi,
                                 const float* __restrict__ Whh0,
                                 const float* __restrict__ bhh0,
                                 const float* __restrict__ Wih1,
                                 const float* __restrict__ bih1,
                                 const float* __restrict__ Whh1,
                                 const float* __restrict__ bhh1,
                                 const float* __restrict__ fcw,
                                 const float* __restrict__ fcb,
                                 float* __restrict__ out)
{
    __shared__ __align__(16) unsigned short h0d[4][8][B_BLK][8];  // 8 KB ring
    __shared__ __align__(16) unsigned short h1d[4][8][B_BLK][8];  // 8 KB ring
    __shared__ __align__(16) float pbuf[4][B_BLK][LDP];           // 49 KB ring
    __shared__ float fcbuf[B_BLK][68];
    __shared__ unsigned h0flag[4], h1flag[4];

    const int tid  = threadIdx.x;
    const int w    = tid >> 6;        // wave 0..11
    const int l    = tid & 63;
    const int c    = l & 15;          // batch-in-block / MFMA col
    const int kg   = l >> 4;          // 0..3
    const int blk  = blockIdx.x;
    const int role = w >> 2;          // 0 = L0, 1 = P, 2 = L1
    const int sub  = w & 3;
    const int jw   = sub * 16;

    // ---- stationary weight fragments + bias C-inits (exp2-prescaled) ----
    short8 frag[6];
    f32x4  bC[3];
    {
        const float* Wsel = (role == 0) ? Whh0 : (role == 1) ? Wih1 : Whh1;
#pragma unroll
        for (int g = 0; g < 3; ++g) {
            const float sc = (g == 2) ? 2.f * LOG2E : LOG2E;
#pragma unroll
            for (int ks = 0; ks < 2; ++ks) {
                const size_t roff = (size_t)(g * 64 + jw + c) * HID + ks * 32 + kg * 8;
                short8 s;
#pragma unroll
                for (int j = 0; j < 8; ++j) s[j] = (short)f2bf(Wsel[roff + j] * sc);
                frag[g * 2 + ks] = s;
            }
            float4 vh0 = *(const float4*)&bhh0[g * 64 + jw + kg * 4];
            float4 vi1 = *(const float4*)&bih1[g * 64 + jw + kg * 4];
            float4 vh1 = *(const float4*)&bhh1[g * 64 + jw + kg * 4];
            if (role == 0) {
                bC[g] = (f32x4){vh0.x * sc, vh0.y * sc, vh0.z * sc, vh0.w * sc};
            } else if (role == 1) {
                if (g < 2)
                    bC[g] = (f32x4){(vi1.x + vh1.x) * sc, (vi1.y + vh1.y) * sc,
                                    (vi1.z + vh1.z) * sc, (vi1.w + vh1.w) * sc};
                else
                    bC[g] = (f32x4){vi1.x * sc, vi1.y * sc, vi1.z * sc, vi1.w * sc};
            } else {
                if (g < 2) bC[g] = (f32x4){0.f, 0.f, 0.f, 0.f};
                else       bC[g] = (f32x4){vh1.x * sc, vh1.y * sc, vh1.z * sc, vh1.w * sc};
            }
        }
    }

    float hst[4] = {0.f, 0.f, 0.f, 0.f};   // L0: h0 slice; L1: h1 slice

    // zero h rings (2048 dwords each) + flags
    for (int i = tid; i < 2048; i += 768) {
        ((unsigned int*)h0d)[i] = 0;
        ((unsigned int*)h1d)[i] = 0;
    }
    if (tid < 4) { h0flag[tid] = 0; h1flag[tid] = 0; }
    __syncthreads();

    const int chunk = 2 * sub + (kg >> 1);
    const int coff  = (kg & 1) * 4;

    if (role == 0) {
        __builtin_amdgcn_s_setprio(1);     // L0 carries the serial h0 chain
        const size_t xstep = (size_t)BATCH * G3;
        const float* xp = xi + (size_t)(blk * B_BLK + c) * G3 + jw + kg * 4;
        float4 pA[3], pB[3];
        pA[0] = *(const float4*)(xp);
        pA[1] = *(const float4*)(xp + 64);
        pA[2] = *(const float4*)(xp + 128);
        pB[0] = *(const float4*)(xp + xstep);
        pB[1] = *(const float4*)(xp + xstep + 64);
        pB[2] = *(const float4*)(xp + xstep + 128);
        const float* xpr = xp + 2 * xstep;

        auto stepL0 = [&](int t, float4 (&cur)[3]) {
            const int pb = (t + 3) & 3;                    // (t-1)&3
            short8 x0 = *(const short8*)&h0d[pb][kg][c][0];
            short8 x1 = *(const short8*)&h0d[pb][4 + kg][c][0];
            f32x4 a0 = bC[0], a1 = bC[1], a2 = bC[2];
            a0 = __builtin_amdgcn_mfma_f32_16x16x32_bf16(frag[0], x0, a0, 0, 0, 0);
            a0 = __builtin_amdgcn_mfma_f32_16x16x32_bf16(frag[1], x1, a0, 0, 0, 0);
            a1 = __builtin_amdgcn_mfma_f32_16x16x32_bf16(frag[2], x0, a1, 0, 0, 0);
            a1 = __builtin_amdgcn_mfma_f32_16x16x32_bf16(frag[3], x1, a1, 0, 0, 0);
            a2 = __builtin_amdgcn_mfma_f32_16x16x32_bf16(frag[4], x0, a2, 0, 0, 0);
            a2 = __builtin_amdgcn_mfma_f32_16x16x32_bf16(frag[5], x1, a2, 0, 0, 0);

            float4 xr4 = cur[0], xz4 = cur[1], xn4 = cur[2];
            if (t + 2 < T_STEPS) {       // refill; rides across sync points
                cur[0] = *(const float4*)(xpr);
                cur[1] = *(const float4*)(xpr + 64);
                cur[2] = *(const float4*)(xpr + 128);
                xpr += xstep;
            }
            hst[0] = gunit(xr4.x + a0[0], xz4.x + a1[0], a2[0], xn4.x, hst[0]);
            hst[1] = gunit(xr4.y + a0[1], xz4.y + a1[1], a2[1], xn4.y, hst[1]);
            hst[2] = gunit(xr4.z + a0[2], xz4.z + a1[2], a2[2], xn4.z, hst[2]);
            hst[3] = gunit(xr4.w + a0[3], xz4.w + a1[3], a2[3], xn4.w, hst[3]);
            uint2 hw;
            hw.x = cvtpk(hst[0], hst[1]);
            hw.y = cvtpk(hst[2], hst[3]);
            *(uint2*)&h0d[t & 3][chunk][c][coff] = hw;
        };

        for (int r = 0; r < 256; ++r) {
            stepL0(2 * r, pA);
            flag_signal(&h0flag[sub], (unsigned)(2 * r + 1));
            __builtin_amdgcn_s_setprio(0);
            flag_wait(h0flag, (unsigned)(2 * r + 1));
            __builtin_amdgcn_s_setprio(1);
            stepL0(2 * r + 1, pB);
            wg_barrier();
        }
        wg_barrier();                      // rounds 256, 257 (L0 idle)
        wg_barrier();
    } else if (role == 1) {
        // ---- P: p(k) = Wih1@h0(k) + biases ----
        auto stepP = [&](int k) {
            const int pb = k & 3;
            short8 x0 = *(const short8*)&h0d[pb][kg][c][0];
            short8 x1 = *(const short8*)&h0d[pb][4 + kg][c][0];
            f32x4 p0 = bC[0], p1 = bC[1], p2 = bC[2];
            p0 = __builtin_amdgcn_mfma_f32_16x16x32_bf16(frag[0], x0, p0, 0, 0, 0);
            p0 = __builtin_amdgcn_mfma_f32_16x16x32_bf16(frag[1], x1, p0, 0, 0, 0);
            p1 = __builtin_amdgcn_mfma_f32_16x16x32_bf16(frag[2], x0, p1, 0, 0, 0);
            p1 = __builtin_amdgcn_mfma_f32_16x16x32_bf16(frag[3], x1, p1, 0, 0, 0);
            p2 = __builtin_amdgcn_mfma_f32_16x16x32_bf16(frag[4], x0, p2, 0, 0, 0);
            p2 = __builtin_amdgcn_mfma_f32_16x16x32_bf16(frag[5], x1, p2, 0, 0, 0);
            float* pd = &pbuf[k & 3][c][jw + kg * 4];
            *(f32x4*)(pd)       = p0;
            *(f32x4*)(pd + 64)  = p1;
            *(f32x4*)(pd + 128) = p2;
        };
        for (int r = 0; r < ROUNDS; ++r) {
            if (r >= 1 && r <= 256) {
                stepP(2 * r - 2);
                stepP(2 * r - 1);
            }
            wg_barrier();
        }
    } else {
        // ---- L1: h1(k) = gates(p(k), Whh1@h1(k-1)) ----
        auto stepL1 = [&](int k) {
            const int py = (k + 3) & 3;                    // (k-1)&3
            short8 y0 = *(const short8*)&h1d[py][kg][c][0];
            short8 y1 = *(const short8*)&h1d[py][4 + kg][c][0];
            f32x4 g0 = bC[0], g1 = bC[1], g2 = bC[2];
            g0 = __builtin_amdgcn_mfma_f32_16x16x32_bf16(frag[0], y0, g0, 0, 0, 0);
            g0 = __builtin_amdgcn_mfma_f32_16x16x32_bf16(frag[1], y1, g0, 0, 0, 0);
            g1 = __builtin_amdgcn_mfma_f32_16x16x32_bf16(frag[2], y0, g1, 0, 0, 0);
            g1 = __builtin_amdgcn_mfma_f32_16x16x32_bf16(frag[3], y1, g1, 0, 0, 0);
            g2 = __builtin_amdgcn_mfma_f32_16x16x32_bf16(frag[4], y0, g2, 0, 0, 0);
            g2 = __builtin_amdgcn_mfma_f32_16x16x32_bf16(frag[5], y1, g2, 0, 0, 0);

            const float* pd = &pbuf[k & 3][c][jw + kg * 4];
            f32x4 pr = *(const f32x4*)(pd);
            f32x4 pz = *(const f32x4*)(pd + 64);
            f32x4 pn = *(const f32x4*)(pd + 128);
#pragma unroll
            for (int q = 0; q < 4; ++q)
                hst[q] = gunit(pr[q] + g0[q], pz[q] + g1[q], g2[q], pn[q], hst[q]);
            uint2 hw;
            hw.x = cvtpk(hst[0], hst[1]);
            hw.y = cvtpk(hst[2], hst[3]);
            *(uint2*)&h1d[k & 3][chunk][c][coff] = hw;
        };
        for (int r = 0; r < ROUNDS; ++r) {
            if (r >= 2) {
                stepL1(2 * r - 4);
                flag_signal(&h1flag[sub], (unsigned)(2 * r - 3));
                flag_wait(h1flag, (unsigned)(2 * r - 3));
                stepL1(2 * r - 3);
            }
            wg_barrier();
        }
    }

    // ---- FC: out[b] = h1(511) . fc_w + fc_b ----
    if (role == 2) {
#pragma unroll
        for (int q = 0; q < 4; ++q)
            fcbuf[c][jw + kg * 4 + q] = hst[q];
    }
    __syncthreads();
    if (w == 0) {
        float p = 0.f;
#pragma unroll
        for (int jj = 0; jj < 16; ++jj)
            p += fcbuf[c][kg * 16 + jj] * fcw[kg * 16 + jj];
        p += __shfl_xor(p, 16);
        p += __shfl_xor(p, 32);
        if (kg == 0) out[blk * B_BLK + c] = p + fcb[0];
    }
}

extern "C" void kernel_launch(void* const* d_in, const int* in_sizes, int n_in,
                              void* d_out, int out_size, void* d_ws, size_t ws_size,
                              hipStream_t stream)
{
    const float* x    = (const float*)d_in[0];
    const float* Wih0 = (const float*)d_in[1];
    const float* Whh0 = (const float*)d_in[2];
    const float* bih0 = (const float*)d_in[3];
    const float* bhh0 = (const float*)d_in[4];
    const float* Wih1 = (const float*)d_in[5];
    const float* Whh1 = (const float*)d_in[6];
    const float* bih1 = (const float*)d_in[7];
    const float* bhh1 = (const float*)d_in[8];
    const float* fcw  = (const float*)d_in[9];
    const float* fcb  = (const float*)d_in[10];
    float* out = (float*)d_out;
    float* xi  = (float*)d_ws;   // 512*64*192 f32 = 25.2 MB (pre-scaled)

    hipLaunchKernelGGL(proj0_kernel, dim3(32768 / BM), dim3(512), 0, stream,
                       x, Wih0, bih0, xi);
    hipLaunchKernelGGL(gru_fused_kernel, dim3(NBLK), dim3(768), 0, stream,
                       xi, Whh0, bhh0, Wih1, bih1, Whh1, bhh1, fcw, fcb, out);
}